// Round 10
// baseline (1706.393 us; speedup 1.0000x reference)
//
#include <hip/hip_runtime.h>

typedef _Float16 half8 __attribute__((ext_vector_type(8)));
typedef float f32x4 __attribute__((ext_vector_type(4)));

#define VD   512
#define HM   1024
#define MPAD 144
#define BSENT 129

// ---------------- workspace layout ----------------
static constexpr size_t SZ_SWIH = (size_t)4096 * 512 * 2;
static constexpr size_t SZ_W1K  = (size_t)4096 * 1024 * 2;
static constexpr size_t OFF_SWIH = 0;
static constexpr size_t OFF_SWHH = OFF_SWIH + SZ_SWIH;
static constexpr size_t OFF_PWIH = OFF_SWHH + SZ_W1K;
static constexpr size_t OFF_PWHH = OFF_PWIH + SZ_W1K;
static constexpr size_t OFF_BWIH = OFF_PWHH + SZ_W1K;
static constexpr size_t OFF_BWHH = OFF_BWIH + SZ_W1K;
static constexpr size_t OFF_SB   = OFF_BWHH + SZ_W1K;
static constexpr size_t OFF_PB   = OFF_SB + (size_t)4096 * 4;
static constexpr size_t OFF_BB   = OFF_PB + (size_t)4096 * 4;
static constexpr size_t OFF_X16  = OFF_BB + (size_t)4096 * 4;
static constexpr size_t SZ_X16   = (size_t)64 * MPAD * VD * 2;
static constexpr size_t OFF_STATE = OFF_X16 + SZ_X16;
static constexpr size_t OFF_H    = OFF_STATE;                 // [2][144][1024] f16
static constexpr size_t SZ_H     = (size_t)2 * MPAD * HM * 2;
static constexpr size_t OFF_HP   = OFF_H + SZ_H;              // [17][8][1024] f16
static constexpr size_t SZ_HP    = (size_t)17 * 8 * HM * 2;
static constexpr size_t OFF_HB   = OFF_HP + SZ_HP;            // [9][1024] f16
static constexpr size_t SZ_HB    = (size_t)9 * HM * 2;
static constexpr size_t OFF_C32  = OFF_HB + SZ_HB;            // [144][1024] f32
static constexpr size_t SZ_C32   = (size_t)MPAD * HM * 4;
static constexpr size_t OFF_CP   = OFF_C32 + SZ_C32;          // [8][1024] f32
static constexpr size_t SZ_CP    = (size_t)8 * HM * 4;
static constexpr size_t OFF_CB   = OFF_CP + SZ_CP;            // [1024] f32
static constexpr size_t OFF_RH   = OFF_CB + (size_t)HM * 4;   // [1024] f32 r_hidden
static constexpr size_t STATE_BYTES = (OFF_RH + (size_t)HM * 4) - OFF_STATE;

// ---------------- helpers ----------------
__device__ __forceinline__ half8 h8z() {
    half8 z = {(_Float16)0,(_Float16)0,(_Float16)0,(_Float16)0,
               (_Float16)0,(_Float16)0,(_Float16)0,(_Float16)0};
    return z;
}

__device__ __forceinline__ half8 ld8(const _Float16* p) {
    return *reinterpret_cast<const half8*>(p);
}

__device__ __forceinline__ void lstm_cell(float ip, float fp, float gp, float op,
                                          float& c, float& h) {
    float ig = 1.0f / (1.0f + expf(-ip));
    float fg = 1.0f / (1.0f + expf(-fp));
    float og = 1.0f / (1.0f + expf(-op));
    float gv = tanhf(gp);
    c = fg * c + ig * gv;
    h = og * tanhf(c);
}

// ---------------- prep kernels ----------------
__global__ void k_cvt(const float* __restrict__ s, _Float16* __restrict__ d, int n) {
    for (int i = blockIdx.x * blockDim.x + threadIdx.x; i < n; i += gridDim.x * blockDim.x)
        d[i] = (_Float16)s[i];
}

__global__ void k_bias(const float* a1, const float* a2, const float* b1, const float* b2,
                       const float* c1, const float* c2,
                       float* sb, float* pb, float* bb) {
    int i = blockIdx.x * blockDim.x + threadIdx.x;
    if (i < 4096) {
        sb[i] = a1[i] + a2[i];
        pb[i] = b1[i] + b2[i];
        bb[i] = c1[i] + c2[i];
    }
}

// X16[t][row][d]; row 0 = headline, rows 1..128 = body sentences, 129..143 zero pad
__global__ void k_gather(const int* __restrict__ head, const int* __restrict__ body,
                         const float* __restrict__ emb, _Float16* __restrict__ X16) {
    const int total = 64 * MPAD * VD;
    for (int idx = blockIdx.x * blockDim.x + threadIdx.x; idx < total;
         idx += gridDim.x * blockDim.x) {
        int d   = idx & (VD - 1);
        int rt  = idx >> 9;
        int row = rt % MPAD;
        int t   = rt / MPAD;
        float v = 0.0f;
        if (row == 0)         v = emb[(size_t)head[t] * VD + d];
        else if (row < BSENT) v = emb[(size_t)body[(row - 1) * 64 + t] * VD + d];
        X16[idx] = (_Float16)v;
    }
}

// ---------------- per-step kernels (kernel boundary = the barrier) ----------------
// All three reuse the r5/r6-proven compute mapping:
// 256 blocks x 512 thr (8 waves). Block owns 4 hidden units (16 gate cols).
// grow = weight row for MFMA B-col l15; K split across waves; LDS reduce; the
// LSTM cell state lives in f32 workspace (block-private addresses, plain RMW —
// kernel boundaries provide all cross-launch coherence).

// Sentence step t: batch 129 (pad 144), K = 512 (x) + 1024 (h).
// Waves g=wv&3 own row-tiles {g, g+4, (g==0: 8)}; kh=wv>>2 splits K 2-way.
__global__ void __launch_bounds__(512)
k_sstep(int t,
        const _Float16* __restrict__ sWih, const _Float16* __restrict__ sWhh,
        const float* __restrict__ sb, const _Float16* __restrict__ X16,
        _Float16* H, float* c32, float* rhid)
{
    __shared__ float lds[8][3][16][17];

    const int tid  = threadIdx.x;
    const int lane = tid & 63;
    const int wv   = tid >> 6;
    const int g    = wv & 3;
    const int kh   = wv >> 2;
    const int l15  = lane & 15;
    const int krow = lane >> 4;
    const int rr   = lane >> 2;
    const int mm   = lane & 3;
    const int ubase = blockIdx.x * 4;
    const int uo    = ubase + mm;
    const int grow  = (l15 >> 2) * HM + ubase + (l15 & 3);

    const float sbi = sb[uo], sbf = sb[1024 + uo], sbg = sb[2048 + uo], sbo = sb[3072 + uo];

    const int rA0 = g * 16 + l15;
    const int rA1 = rA0 + 64;
    const int rA2 = 128 + l15;

    const _Float16* Xt = X16 + (size_t)t * MPAD * VD;
    const _Float16* Hr = H + (size_t)(t & 1) * MPAD * HM;
    _Float16*       Hw = H + (size_t)((t + 1) & 1) * MPAD * HM;

    f32x4 a0 = {0.f,0.f,0.f,0.f}, a1 = {0.f,0.f,0.f,0.f}, a2 = {0.f,0.f,0.f,0.f};
    if (kh == 0) {
        // x part: K 0..511
#pragma unroll
        for (int kt = 0; kt < 16; ++kt) {
            const int kk = kt * 32 + krow * 8;
            half8 b  = ld8(sWih + (size_t)grow * VD + kk);
            half8 x0 = ld8(Xt + (size_t)rA0 * VD + kk);
            half8 x1 = ld8(Xt + (size_t)rA1 * VD + kk);
            a0 = __builtin_amdgcn_mfma_f32_16x16x32_f16(x0, b, a0, 0, 0, 0);
            a1 = __builtin_amdgcn_mfma_f32_16x16x32_f16(x1, b, a1, 0, 0, 0);
            if (g == 0) {
                half8 x2 = ld8(Xt + (size_t)rA2 * VD + kk);
                a2 = __builtin_amdgcn_mfma_f32_16x16x32_f16(x2, b, a2, 0, 0, 0);
            }
        }
        // h part: K-tiles 0..7
#pragma unroll
        for (int kt = 0; kt < 8; ++kt) {
            const int kk = kt * 32 + krow * 8;
            half8 b  = ld8(sWhh + (size_t)grow * HM + kk);
            half8 h0 = ld8(Hr + (size_t)rA0 * HM + kk);
            half8 h1 = ld8(Hr + (size_t)rA1 * HM + kk);
            a0 = __builtin_amdgcn_mfma_f32_16x16x32_f16(h0, b, a0, 0, 0, 0);
            a1 = __builtin_amdgcn_mfma_f32_16x16x32_f16(h1, b, a1, 0, 0, 0);
            if (g == 0) {
                half8 h2 = ld8(Hr + (size_t)rA2 * HM + kk);
                a2 = __builtin_amdgcn_mfma_f32_16x16x32_f16(h2, b, a2, 0, 0, 0);
            }
        }
    } else {
        // h part: K-tiles 8..31
#pragma unroll
        for (int kt = 0; kt < 24; ++kt) {
            const int kk = (8 + kt) * 32 + krow * 8;
            half8 b  = ld8(sWhh + (size_t)grow * HM + kk);
            half8 h0 = ld8(Hr + (size_t)rA0 * HM + kk);
            half8 h1 = ld8(Hr + (size_t)rA1 * HM + kk);
            a0 = __builtin_amdgcn_mfma_f32_16x16x32_f16(h0, b, a0, 0, 0, 0);
            a1 = __builtin_amdgcn_mfma_f32_16x16x32_f16(h1, b, a1, 0, 0, 0);
            if (g == 0) {
                half8 h2 = ld8(Hr + (size_t)rA2 * HM + kk);
                a2 = __builtin_amdgcn_mfma_f32_16x16x32_f16(h2, b, a2, 0, 0, 0);
            }
        }
    }
    // stash K-half partials
#pragma unroll
    for (int q = 0; q < 4; ++q) {
        lds[wv][0][krow * 4 + q][l15] = a0[q];
        lds[wv][1][krow * 4 + q][l15] = a1[q];
    }
    if (g == 0) {
#pragma unroll
        for (int q = 0; q < 4; ++q) lds[wv][2][krow * 4 + q][l15] = a2[q];
    }
    __syncthreads();
    // epilogue: wave T reduces the two K-half partials of tile T
    {
        const int T  = wv;
        const int wA = (T < 4) ? T     : T - 4;
        const int wB = (T < 4) ? T + 4 : T;
        const int jj = (T < 4) ? 0 : 1;
        const int rowg = T * 16 + rr;
        if (rowg < BSENT) {
            float ip = lds[wA][jj][rr][ 0 + mm] + lds[wB][jj][rr][ 0 + mm] + sbi;
            float fp = lds[wA][jj][rr][ 4 + mm] + lds[wB][jj][rr][ 4 + mm] + sbf;
            float gp = lds[wA][jj][rr][ 8 + mm] + lds[wB][jj][rr][ 8 + mm] + sbg;
            float op = lds[wA][jj][rr][12 + mm] + lds[wB][jj][rr][12 + mm] + sbo;
            const size_t o = (size_t)rowg * HM + uo;
            float c = c32[o], h;
            lstm_cell(ip, fp, gp, op, c, h);
            c32[o] = c;
            Hw[o]  = (_Float16)h;
            if (t == 63 && rowg == 0) rhid[uo] = h;
        }
    }
    if (wv == 0) {   // tile 8: only row 128 valid
        const int rowg = 128 + rr;
        if (rowg < BSENT) {
            float ip = lds[0][2][rr][ 0 + mm] + lds[4][2][rr][ 0 + mm] + sbi;
            float fp = lds[0][2][rr][ 4 + mm] + lds[4][2][rr][ 4 + mm] + sbf;
            float gp = lds[0][2][rr][ 8 + mm] + lds[4][2][rr][ 8 + mm] + sbg;
            float op = lds[0][2][rr][12 + mm] + lds[4][2][rr][12 + mm] + sbo;
            const size_t o = (size_t)rowg * HM + uo;
            float c = c32[o], h;
            lstm_cell(ip, fp, gp, op, c, h);
            c32[o] = c;
            Hw[o]  = (_Float16)h;
        }
    }
}

// Paragraph step s: batch 8 (pad 16), K = 1024 (sent_h) + 1024 (h_para),
// split 8-way across waves (wv<4: ih, wv>=4: hh).
__global__ void __launch_bounds__(512)
k_pstep(int s,
        const _Float16* __restrict__ pWih, const _Float16* __restrict__ pWhh,
        const float* __restrict__ pb, const _Float16* __restrict__ H,
        _Float16* HP, float* cp32)
{
    __shared__ float lds[8][16][17];

    const int tid  = threadIdx.x;
    const int lane = tid & 63;
    const int wv   = tid >> 6;
    const int l15  = lane & 15;
    const int krow = lane >> 4;
    const int rr   = lane >> 2;
    const int mm   = lane & 3;
    const int ubase = blockIdx.x * 4;
    const int uo    = ubase + mm;
    const int grow  = (l15 >> 2) * HM + ubase + (l15 & 3);

    const _Float16* HPr = HP + (size_t)s * 8 * HM;
    _Float16*       HPw = HP + (size_t)(s + 1) * 8 * HM;

    f32x4 acc = {0.f,0.f,0.f,0.f};
    if (wv < 4) {
        const int rs = 1 + l15 * 16 + s;                  // sent_h[p=l15][s]
#pragma unroll
        for (int k = 0; k < 8; ++k) {
            const int kk = (wv * 8 + k) * 32 + krow * 8;
            half8 b = ld8(pWih + (size_t)grow * HM + kk);
            half8 a = h8z();
            if (l15 < 8) a = ld8(H + (size_t)rs * HM + kk);
            acc = __builtin_amdgcn_mfma_f32_16x16x32_f16(a, b, acc, 0, 0, 0);
        }
    } else {
#pragma unroll
        for (int k = 0; k < 8; ++k) {
            const int kk = ((wv - 4) * 8 + k) * 32 + krow * 8;
            half8 b = ld8(pWhh + (size_t)grow * HM + kk);
            half8 a = h8z();
            if (l15 < 8) a = ld8(HPr + (size_t)l15 * HM + kk);
            acc = __builtin_amdgcn_mfma_f32_16x16x32_f16(a, b, acc, 0, 0, 0);
        }
    }
#pragma unroll
    for (int q = 0; q < 4; ++q) lds[wv][krow * 4 + q][l15] = acc[q];
    __syncthreads();
    if (wv == 0 && rr < 8) {
        float ip = pb[uo], fp = pb[1024 + uo], gp = pb[2048 + uo], op = pb[3072 + uo];
#pragma unroll
        for (int w = 0; w < 8; ++w) {
            ip += lds[w][rr][ 0 + mm];
            fp += lds[w][rr][ 4 + mm];
            gp += lds[w][rr][ 8 + mm];
            op += lds[w][rr][12 + mm];
        }
        const size_t o = (size_t)rr * HM + uo;
        float c = cp32[o], h;
        lstm_cell(ip, fp, gp, op, c, h);
        cp32[o] = c;
        HPw[o]  = (_Float16)h;
    }
}

// Body step t: batch 1, K = 1024 (para_h) + 1024 (h_body), 8-way wave split.
__global__ void __launch_bounds__(512)
k_bstep(int t,
        const _Float16* __restrict__ bWih, const _Float16* __restrict__ bWhh,
        const float* __restrict__ bb, const _Float16* __restrict__ HP,
        _Float16* HB, float* cb32, const float* __restrict__ rhid, float* out)
{
    __shared__ float lds[8][16][17];

    const int tid  = threadIdx.x;
    const int lane = tid & 63;
    const int wv   = tid >> 6;
    const int l15  = lane & 15;
    const int krow = lane >> 4;
    const int rr   = lane >> 2;
    const int mm   = lane & 3;
    const int ubase = blockIdx.x * 4;
    const int uo    = ubase + mm;
    const int grow  = (l15 >> 2) * HM + ubase + (l15 & 3);

    const _Float16* HPf = HP + (size_t)16 * 8 * HM;   // para-final h
    const _Float16* HBr = HB + (size_t)t * HM;
    _Float16*       HBw = HB + (size_t)(t + 1) * HM;

    f32x4 acc = {0.f,0.f,0.f,0.f};
    if (wv < 4) {
#pragma unroll
        for (int k = 0; k < 8; ++k) {
            const int kk = (wv * 8 + k) * 32 + krow * 8;
            half8 b = ld8(bWih + (size_t)grow * HM + kk);
            half8 a = h8z();
            if (l15 == 0) a = ld8(HPf + (size_t)t * HM + kk);
            acc = __builtin_amdgcn_mfma_f32_16x16x32_f16(a, b, acc, 0, 0, 0);
        }
    } else {
#pragma unroll
        for (int k = 0; k < 8; ++k) {
            const int kk = ((wv - 4) * 8 + k) * 32 + krow * 8;
            half8 b = ld8(bWhh + (size_t)grow * HM + kk);
            half8 a = h8z();
            if (l15 == 0) a = ld8(HBr + kk);
            acc = __builtin_amdgcn_mfma_f32_16x16x32_f16(a, b, acc, 0, 0, 0);
        }
    }
#pragma unroll
    for (int q = 0; q < 4; ++q) lds[wv][krow * 4 + q][l15] = acc[q];
    __syncthreads();
    if (wv == 0 && rr == 0) {   // lanes 0..3
        float ip = bb[uo], fp = bb[1024 + uo], gp = bb[2048 + uo], op = bb[3072 + uo];
#pragma unroll
        for (int w = 0; w < 8; ++w) {
            ip += lds[w][0][ 0 + mm];
            fp += lds[w][0][ 4 + mm];
            gp += lds[w][0][ 8 + mm];
            op += lds[w][0][12 + mm];
        }
        float c = cb32[uo], h;
        lstm_cell(ip, fp, gp, op, c, h);
        cb32[uo] = c;
        HBw[uo]  = (_Float16)h;
        if (t == 7) {
            out[uo]        = h;          // h_body
            out[1024 + uo] = rhid[uo];   // r_hidden
        }
    }
}

// ---------------- host ----------------
extern "C" void kernel_launch(void* const* d_in, const int* in_sizes, int n_in,
                              void* d_out, int out_size, void* d_ws, size_t ws_size,
                              hipStream_t stream) {
    const int*   head  = (const int*)d_in[0];
    const int*   body  = (const int*)d_in[1];
    const float* emb   = (const float*)d_in[2];
    const float* sWihF = (const float*)d_in[3];
    const float* sWhhF = (const float*)d_in[4];
    const float* sbih  = (const float*)d_in[5];
    const float* sbhh  = (const float*)d_in[6];
    const float* pWihF = (const float*)d_in[7];
    const float* pWhhF = (const float*)d_in[8];
    const float* pbih  = (const float*)d_in[9];
    const float* pbhh  = (const float*)d_in[10];
    const float* bWihF = (const float*)d_in[11];
    const float* bWhhF = (const float*)d_in[12];
    const float* bbih  = (const float*)d_in[13];
    const float* bbhh  = (const float*)d_in[14];

    char* ws = (char*)d_ws;
    _Float16* sWih16 = (_Float16*)(ws + OFF_SWIH);
    _Float16* sWhh16 = (_Float16*)(ws + OFF_SWHH);
    _Float16* pWih16 = (_Float16*)(ws + OFF_PWIH);
    _Float16* pWhh16 = (_Float16*)(ws + OFF_PWHH);
    _Float16* bWih16 = (_Float16*)(ws + OFF_BWIH);
    _Float16* bWhh16 = (_Float16*)(ws + OFF_BWHH);
    float*    sbp    = (float*)(ws + OFF_SB);
    float*    pbp    = (float*)(ws + OFF_PB);
    float*    bbp    = (float*)(ws + OFF_BB);
    _Float16* X16    = (_Float16*)(ws + OFF_X16);
    _Float16* Hp     = (_Float16*)(ws + OFF_H);
    _Float16* HPp    = (_Float16*)(ws + OFF_HP);
    _Float16* HBp    = (_Float16*)(ws + OFF_HB);
    float*    c32p   = (float*)(ws + OFF_C32);
    float*    cp32p  = (float*)(ws + OFF_CP);
    float*    cb32p  = (float*)(ws + OFF_CB);
    float*    rhidp  = (float*)(ws + OFF_RH);
    float*    outp   = (float*)d_out;

    hipMemsetAsync(ws + OFF_STATE, 0, STATE_BYTES, stream);
    k_cvt<<<512, 256, 0, stream>>>(sWihF, sWih16, 4096 * 512);
    k_cvt<<<1024, 256, 0, stream>>>(sWhhF, sWhh16, 4096 * 1024);
    k_cvt<<<1024, 256, 0, stream>>>(pWihF, pWih16, 4096 * 1024);
    k_cvt<<<1024, 256, 0, stream>>>(pWhhF, pWhh16, 4096 * 1024);
    k_cvt<<<1024, 256, 0, stream>>>(bWihF, bWih16, 4096 * 1024);
    k_cvt<<<1024, 256, 0, stream>>>(bWhhF, bWhh16, 4096 * 1024);
    k_bias<<<16, 256, 0, stream>>>(sbih, sbhh, pbih, pbhh, bbih, bbhh, sbp, pbp, bbp);
    k_gather<<<2048, 256, 0, stream>>>(head, body, emb, X16);

    for (int t = 0; t < 64; ++t)
        k_sstep<<<256, 512, 0, stream>>>(t, sWih16, sWhh16, sbp, X16, Hp, c32p, rhidp);
    for (int s = 0; s < 16; ++s)
        k_pstep<<<256, 512, 0, stream>>>(s, pWih16, pWhh16, pbp, Hp, HPp, cp32p);
    for (int t = 0; t < 8; ++t)
        k_bstep<<<256, 512, 0, stream>>>(t, bWih16, bWhh16, bbp, HPp, HBp, cb32p,
                                         rhidp, outp);
}